// Round 1
// baseline (50.819 us; speedup 1.0000x reference)
//
#include <hip/hip_runtime.h>

// pred: [T=2048, B=64, C=512] f32, mask: [T*B, 1] f32.
// loss = -sum_{p>0.9} p / max(cnt,1), 0 if cnt==0.
// Only the per-row argmax can exceed 0.9 (probs sum to 1), so per row:
//   m = max(x), s = sum exp(x-m), pmax = 1/s; selected iff pmax > 0.9.

#define NCLS 512
#define THRESH 0.9f

__global__ void pl_init(float* ws) {
    ws[0] = 0.0f;                        // running total of selected p
    ((unsigned int*)ws)[1] = 0u;         // selected count
}

__global__ __launch_bounds__(256) void pl_main(const float* __restrict__ pred,
                                               const float* __restrict__ mask,
                                               float* __restrict__ ws,
                                               int N) {
    const int lane = threadIdx.x & 63;
    const int wid  = threadIdx.x >> 6;   // 4 waves per block

    __shared__ float sTotal;
    __shared__ unsigned int sCnt;
    if (threadIdx.x == 0) { sTotal = 0.0f; sCnt = 0u; }
    __syncthreads();

    float wTotal = 0.0f;
    unsigned int wCnt = 0u;

    const long long rstride = (long long)gridDim.x * 4;
    for (long long row = (long long)blockIdx.x * 4 + wid; row < N; row += rstride) {
        const float mval = mask[row];
        const float4* rp = (const float4*)(pred + row * NCLS);
        // lane's 8 elements: [lane*4 .. +3] and [256 + lane*4 .. +3]
        float4 a = rp[lane];
        float4 b = rp[lane + 64];
        float x0 = a.x * mval, x1 = a.y * mval, x2 = a.z * mval, x3 = a.w * mval;
        float x4 = b.x * mval, x5 = b.y * mval, x6 = b.z * mval, x7 = b.w * mval;

        float mx = fmaxf(fmaxf(fmaxf(x0, x1), fmaxf(x2, x3)),
                         fmaxf(fmaxf(x4, x5), fmaxf(x6, x7)));
        #pragma unroll
        for (int off = 1; off < 64; off <<= 1)
            mx = fmaxf(mx, __shfl_xor(mx, off));

        float s = __expf(x0 - mx) + __expf(x1 - mx) + __expf(x2 - mx) + __expf(x3 - mx)
                + __expf(x4 - mx) + __expf(x5 - mx) + __expf(x6 - mx) + __expf(x7 - mx);
        #pragma unroll
        for (int off = 1; off < 64; off <<= 1)
            s += __shfl_xor(s, off);

        // p of the argmax element is exp(mx - mx)/s = 1/s
        float pmax = 1.0f / s;
        if (lane == 0 && pmax > THRESH) { wTotal += pmax; wCnt += 1u; }
    }

    if (lane == 0 && wCnt > 0u) {
        atomicAdd(&sTotal, wTotal);
        atomicAdd(&sCnt, wCnt);
    }
    __syncthreads();
    if (threadIdx.x == 0 && sCnt > 0u) {
        atomicAdd(&ws[0], sTotal);
        atomicAdd((unsigned int*)ws + 1, sCnt);
    }
}

__global__ void pl_final(const float* __restrict__ ws, float* __restrict__ out) {
    unsigned int cnt = ((const unsigned int*)ws)[1];
    out[0] = (cnt > 0u) ? (-ws[0] / (float)cnt) : 0.0f;
}

extern "C" void kernel_launch(void* const* d_in, const int* in_sizes, int n_in,
                              void* d_out, int out_size, void* d_ws, size_t ws_size,
                              hipStream_t stream) {
    const float* pred = (const float*)d_in[0];
    const float* mask = (const float*)d_in[1];
    float* out = (float*)d_out;
    float* ws  = (float*)d_ws;

    const int N = in_sizes[0] / NCLS;    // number of rows (T*B)

    pl_init<<<1, 1, 0, stream>>>(ws);

    const int blocks = 2048;             // grid-stride; 4 rows (waves) per block
    pl_main<<<blocks, 256, 0, stream>>>(pred, mask, ws, N);

    pl_final<<<1, 1, 0, stream>>>(ws, out);
}

// Round 2
// 49.298 us; speedup vs baseline: 1.0308x; 1.0308x over previous
//
#include <hip/hip_runtime.h>

// pred: [T=2048, B=64, C=512] f32, mask: [T*B, 1] f32.
// loss = -sum_{p>0.9} p / max(cnt,1), 0 if cnt==0.
// Only the per-row argmax can exceed 0.9 (softmax sums to 1), so per row:
//   m = max(x), s = sum exp(x-m), pmax = 1/s; selected iff pmax > 0.9.
// Two kernels: main writes per-block (total,cnt) partials (plain stores, no
// init needed), final reduces 2048 partials and writes the loss.

#define NCLS 512
#define THRESH 0.9f
#define NBLOCKS 2048

__device__ __forceinline__ void row_reduce(float4 a, float4 b, float mval,
                                           float& wTotal, float& wCnt) {
    float x0 = a.x * mval, x1 = a.y * mval, x2 = a.z * mval, x3 = a.w * mval;
    float x4 = b.x * mval, x5 = b.y * mval, x6 = b.z * mval, x7 = b.w * mval;

    float mx = fmaxf(fmaxf(fmaxf(x0, x1), fmaxf(x2, x3)),
                     fmaxf(fmaxf(x4, x5), fmaxf(x6, x7)));
    #pragma unroll
    for (int off = 1; off < 64; off <<= 1)
        mx = fmaxf(mx, __shfl_xor(mx, off));

    float s = __expf(x0 - mx) + __expf(x1 - mx) + __expf(x2 - mx) + __expf(x3 - mx)
            + __expf(x4 - mx) + __expf(x5 - mx) + __expf(x6 - mx) + __expf(x7 - mx);
    #pragma unroll
    for (int off = 1; off < 64; off <<= 1)
        s += __shfl_xor(s, off);

    float pmax = 1.0f / s;          // prob of the argmax element
    if (pmax > THRESH) { wTotal += pmax; wCnt += 1.0f; }
}

__global__ __launch_bounds__(256) void pl_main(const float* __restrict__ pred,
                                               const float* __restrict__ mask,
                                               float2* __restrict__ partial,
                                               int N) {
    const int lane = threadIdx.x & 63;
    const int wid  = threadIdx.x >> 6;   // 4 waves per block

    float wTotal = 0.0f;
    float wCnt   = 0.0f;

    const long long rstride = (long long)gridDim.x * 4;
    long long row = (long long)blockIdx.x * 4 + wid;

    // unroll x2: keep two rows' loads (4x float4/lane) in flight before
    // either row's dependent shuffle/exp chain starts
    for (; row + rstride < (long long)N; row += 2 * rstride) {
        const long long r2 = row + rstride;
        const float m1 = mask[row];
        const float m2 = mask[r2];
        const float4* rp1 = (const float4*)(pred + row * NCLS);
        const float4* rp2 = (const float4*)(pred + r2 * NCLS);
        float4 a1 = rp1[lane];
        float4 b1 = rp1[lane + 64];
        float4 a2 = rp2[lane];
        float4 b2 = rp2[lane + 64];
        row_reduce(a1, b1, m1, wTotal, wCnt);
        row_reduce(a2, b2, m2, wTotal, wCnt);
    }
    for (; row < (long long)N; row += rstride) {
        const float m1 = mask[row];
        const float4* rp1 = (const float4*)(pred + row * NCLS);
        float4 a1 = rp1[lane];
        float4 b1 = rp1[lane + 64];
        row_reduce(a1, b1, m1, wTotal, wCnt);
    }

    __shared__ float sT[4];
    __shared__ float sC[4];
    if (lane == 0) { sT[wid] = wTotal; sC[wid] = wCnt; }
    __syncthreads();
    if (threadIdx.x == 0) {
        float t = sT[0] + sT[1] + sT[2] + sT[3];
        float c = sC[0] + sC[1] + sC[2] + sC[3];
        partial[blockIdx.x] = make_float2(t, c);
    }
}

__global__ __launch_bounds__(256) void pl_final(const float2* __restrict__ partial,
                                                int nb, float* __restrict__ out) {
    const int lane = threadIdx.x & 63;
    const int wid  = threadIdx.x >> 6;

    float t = 0.0f, c = 0.0f;
    for (int i = threadIdx.x; i < nb; i += 256) {
        float2 p = partial[i];
        t += p.x;
        c += p.y;
    }
    #pragma unroll
    for (int off = 1; off < 64; off <<= 1) {
        t += __shfl_xor(t, off);
        c += __shfl_xor(c, off);
    }
    __shared__ float sT[4];
    __shared__ float sC[4];
    if (lane == 0) { sT[wid] = t; sC[wid] = c; }
    __syncthreads();
    if (threadIdx.x == 0) {
        float tt = sT[0] + sT[1] + sT[2] + sT[3];
        float cc = sC[0] + sC[1] + sC[2] + sC[3];
        out[0] = (cc > 0.0f) ? (-tt / cc) : 0.0f;
    }
}

extern "C" void kernel_launch(void* const* d_in, const int* in_sizes, int n_in,
                              void* d_out, int out_size, void* d_ws, size_t ws_size,
                              hipStream_t stream) {
    const float* pred = (const float*)d_in[0];
    const float* mask = (const float*)d_in[1];
    float* out = (float*)d_out;
    float2* partial = (float2*)d_ws;

    const int N = in_sizes[0] / NCLS;    // number of rows (T*B)

    pl_main<<<NBLOCKS, 256, 0, stream>>>(pred, mask, partial, N);
    pl_final<<<1, 256, 0, stream>>>(partial, NBLOCKS, out);
}